// Round 1
// baseline (420.663 us; speedup 1.0000x reference)
//
#include <hip/hip_runtime.h>

// Problem dims (fixed by setup_inputs)
constexpr int Bb = 4, Cc = 128, Nn = 4096, Kk = 32, Ns = 16384;
constexpr int ROWS = Bb * Nn; // 16384 (b*n) rows

// ---- workspace layout (bytes) ----
constexpr size_t SZ_SEG   = (size_t)Bb * Ns * Cc * 4;   // 32 MB: scatter-max targets (u32 bits of f32)
constexpr size_t OFF_SEG  = 0;
constexpr size_t SZ_GX    = (size_t)ROWS * Cc * 4;      // 8 MB
constexpr size_t OFF_GX   = OFF_SEG + SZ_SEG;           // group-max, row-major (row, c)
constexpr size_t OFF_H1   = OFF_GX + SZ_GX;             // GEMM1 out (row, 128)
constexpr size_t OFF_H2   = OFF_H1 + SZ_GX;             // GEMM2 out (row, 128)
constexpr size_t SZ_FLAGS = (size_t)Bb * Ns;            // 64 KB needed-segment flags
constexpr size_t OFF_FLAGS= OFF_H2 + SZ_GX;
constexpr size_t SZ_PART  = 2 * 128 * 128 * 4;          // 128 KB stats partials
constexpr size_t OFF_PART = OFF_FLAGS + SZ_FLAGS;
constexpr size_t OFF_SC1  = OFF_PART + SZ_PART;
constexpr size_t OFF_SH1  = OFF_SC1 + 512;
constexpr size_t OFF_SC2  = OFF_SH1 + 512;
constexpr size_t OFF_SH2  = OFF_SC2 + 512;

// ---- mark segments that will actually be gathered (fps targets) ----
__global__ void k_setflags(const int* __restrict__ fps, unsigned char* __restrict__ flags) {
    int i = blockIdx.x * 256 + threadIdx.x;     // 0 .. 16383
    if (i < Bb * Nn) {
        int bb = i >> 12;                        // / 4096
        flags[bb * Ns + fps[i]] = 1;
    }
}

// ---- fused: local max over k  +  filtered scatter-max into seg ----
// grid (4096, 4), 256 threads. Block handles one (b, n): 128 channels x 32 k.
__global__ __launch_bounds__(256) void k_groupmax_scatter(
        const float* __restrict__ x, const int* __restrict__ gidx,
        const unsigned char* __restrict__ flags,
        float* __restrict__ gx, unsigned int* __restrict__ seg) {
    int nn = blockIdx.x, bb = blockIdx.y;
    int t = threadIdx.x;
    int kk = t & 31, cr = t >> 5;               // cr: 0..7 channel stripes
    __shared__ float gbuf[128];

    int idxv = gidx[((bb * Nn + nn) << 5) + kk];
    bool need = flags[bb * Ns + idxv] != 0;
    unsigned int segrow = (unsigned int)(bb * Ns + idxv) * 128u;

    const float* xb = x + ((size_t)bb * Cc * Nn + nn) * Kk; // + ch*Nn*Kk + kk
    #pragma unroll
    for (int ch = cr; ch < 128; ch += 8) {
        float v = xb[(size_t)ch * Nn * Kk + kk];
        float m = v;
        #pragma unroll
        for (int off = 16; off; off >>= 1) m = fmaxf(m, __shfl_xor(m, off, 64));
        if (kk == 0) gbuf[ch] = m;
        if (need && v > 0.0f)
            atomicMax(seg + segrow + ch, __float_as_uint(v));
    }
    __syncthreads();
    if (t < 128) gx[((size_t)(bb * Nn + nn)) * 128 + t] = gbuf[t];
}

// ---- GEMM1: h1(row,128) = A(row,256) @ w1^T + b1 ----
// A: k<128 -> gx[row][k]; k>=128 -> seg[fps_row][k-128] (gather fused here)
__global__ __launch_bounds__(256) void k_gemm1(
        const float* __restrict__ gx, const float* __restrict__ segf,
        const int* __restrict__ fps, const float* __restrict__ w1,
        const float* __restrict__ b1, float* __restrict__ h1) {
    __shared__ float As[32][68];    // [kc][row], 64 rows + pad
    __shared__ float Bs[32][132];   // [kc][col], 128 cols + pad
    __shared__ int rowbase[64];
    int t = threadIdx.x;
    int m0 = blockIdx.x * 64;
    if (t < 64) {
        int row = m0 + t;
        rowbase[t] = ((row >> 12) * Ns + fps[row]) * 128;
    }
    int tn = t & 31;    // cols tn*4..+3
    int tm = t >> 5;    // rows tm*8..+7
    float acc[8][4] = {};
    for (int k0 = 0; k0 < 256; k0 += 32) {
        __syncthreads();
        #pragma unroll
        for (int i = 0; i < 2; i++) {           // A: 2048 floats
            int fq = t + i * 256;
            int row = fq >> 3;
            int c4 = (fq & 7) * 4;
            int k = k0 + c4;
            float4 v;
            if (k0 < 128) v = *(const float4*)(gx + (size_t)(m0 + row) * 128 + k);
            else          v = *(const float4*)(segf + rowbase[row] + (k - 128));
            As[c4 + 0][row] = v.x; As[c4 + 1][row] = v.y;
            As[c4 + 2][row] = v.z; As[c4 + 3][row] = v.w;
        }
        #pragma unroll
        for (int i = 0; i < 4; i++) {           // B: w1 chunk 32x128
            int fq = t + i * 256;
            int col = fq >> 3;
            int c4 = (fq & 7) * 4;
            float4 v = *(const float4*)(w1 + (size_t)col * 256 + k0 + c4);
            Bs[c4 + 0][col] = v.x; Bs[c4 + 1][col] = v.y;
            Bs[c4 + 2][col] = v.z; Bs[c4 + 3][col] = v.w;
        }
        __syncthreads();
        #pragma unroll
        for (int kc = 0; kc < 32; kc++) {
            float4 a0 = *(const float4*)&As[kc][tm * 8];
            float4 a1 = *(const float4*)&As[kc][tm * 8 + 4];
            float4 bv = *(const float4*)&Bs[kc][tn * 4];
            float av[8] = {a0.x, a0.y, a0.z, a0.w, a1.x, a1.y, a1.z, a1.w};
            float bw[4] = {bv.x, bv.y, bv.z, bv.w};
            #pragma unroll
            for (int r = 0; r < 8; r++)
                #pragma unroll
                for (int c = 0; c < 4; c++) acc[r][c] += av[r] * bw[c];
        }
    }
    float4 bv = *(const float4*)(b1 + tn * 4);
    #pragma unroll
    for (int r = 0; r < 8; r++) {
        int row = m0 + tm * 8 + r;
        float4 o;
        o.x = acc[r][0] + bv.x; o.y = acc[r][1] + bv.y;
        o.z = acc[r][2] + bv.z; o.w = acc[r][3] + bv.w;
        *(float4*)(h1 + (size_t)row * 128 + tn * 4) = o;
    }
}

// ---- GEMM2: h2(row,128) = relu(bn1(h1)) @ w2^T + b2 ----
__global__ __launch_bounds__(256) void k_gemm2(
        const float* __restrict__ h1, const float* __restrict__ sc1,
        const float* __restrict__ sh1, const float* __restrict__ w2,
        const float* __restrict__ b2, float* __restrict__ h2) {
    __shared__ float As[32][68];
    __shared__ float Bs[32][132];
    __shared__ float ssc[128], ssh[128];
    int t = threadIdx.x;
    int m0 = blockIdx.x * 64;
    if (t < 128) { ssc[t] = sc1[t]; ssh[t] = sh1[t]; }
    int tn = t & 31, tm = t >> 5;
    float acc[8][4] = {};
    for (int k0 = 0; k0 < 128; k0 += 32) {
        __syncthreads();
        #pragma unroll
        for (int i = 0; i < 2; i++) {
            int fq = t + i * 256;
            int row = fq >> 3;
            int c4 = (fq & 7) * 4;
            int k = k0 + c4;
            float4 v = *(const float4*)(h1 + (size_t)(m0 + row) * 128 + k);
            As[c4 + 0][row] = fmaxf(0.f, fmaf(v.x, ssc[k + 0], ssh[k + 0]));
            As[c4 + 1][row] = fmaxf(0.f, fmaf(v.y, ssc[k + 1], ssh[k + 1]));
            As[c4 + 2][row] = fmaxf(0.f, fmaf(v.z, ssc[k + 2], ssh[k + 2]));
            As[c4 + 3][row] = fmaxf(0.f, fmaf(v.w, ssc[k + 3], ssh[k + 3]));
        }
        #pragma unroll
        for (int i = 0; i < 4; i++) {
            int fq = t + i * 256;
            int col = fq >> 3;
            int c4 = (fq & 7) * 4;
            float4 v = *(const float4*)(w2 + (size_t)col * 128 + k0 + c4);
            Bs[c4 + 0][col] = v.x; Bs[c4 + 1][col] = v.y;
            Bs[c4 + 2][col] = v.z; Bs[c4 + 3][col] = v.w;
        }
        __syncthreads();
        #pragma unroll
        for (int kc = 0; kc < 32; kc++) {
            float4 a0 = *(const float4*)&As[kc][tm * 8];
            float4 a1 = *(const float4*)&As[kc][tm * 8 + 4];
            float4 bv = *(const float4*)&Bs[kc][tn * 4];
            float av[8] = {a0.x, a0.y, a0.z, a0.w, a1.x, a1.y, a1.z, a1.w};
            float bw[4] = {bv.x, bv.y, bv.z, bv.w};
            #pragma unroll
            for (int r = 0; r < 8; r++)
                #pragma unroll
                for (int c = 0; c < 4; c++) acc[r][c] += av[r] * bw[c];
        }
    }
    float4 bv = *(const float4*)(b2 + tn * 4);
    #pragma unroll
    for (int r = 0; r < 8; r++) {
        int row = m0 + tm * 8 + r;
        float4 o;
        o.x = acc[r][0] + bv.x; o.y = acc[r][1] + bv.y;
        o.z = acc[r][2] + bv.z; o.w = acc[r][3] + bv.w;
        *(float4*)(h2 + (size_t)row * 128 + tn * 4) = o;
    }
}

// ---- BN stats stage 1: 64 blocks x 256 thr; block reduces 256 rows ----
__global__ __launch_bounds__(256) void k_stats(const float* __restrict__ h,
                                               float* __restrict__ partial) {
    int o = threadIdx.x & 127, rp = threadIdx.x >> 7;
    int blk = blockIdx.x;
    float s = 0.f, sq = 0.f;
    for (int r = blk * 256 + rp; r < blk * 256 + 256; r += 2) {
        float v = h[(size_t)r * 128 + o];
        s += v; sq += v * v;
    }
    partial[(blk * 2 + rp) * 128 + o] = s;
    partial[16384 + (blk * 2 + rp) * 128 + o] = sq;
}

// ---- BN stats stage 2: 1 block x 128 thr -> scale/shift ----
__global__ void k_finalize(const float* __restrict__ partial,
                           const float* __restrict__ g, const float* __restrict__ be,
                           float* __restrict__ scale, float* __restrict__ shift) {
    int o = threadIdx.x;
    float s = 0.f, sq = 0.f;
    for (int j = 0; j < 128; j++) { s += partial[j * 128 + o]; sq += partial[16384 + j * 128 + o]; }
    float mean = s * (1.0f / 16384.0f);
    float var = sq * (1.0f / 16384.0f) - mean * mean;
    float sc = g[o] * rsqrtf(var + 1e-5f);
    scale[o] = sc;
    shift[o] = be[o] - mean * sc;
}

// ---- final: bn2+relu on h2, transpose to (b, c, n) ----
__global__ __launch_bounds__(256) void k_out(const float* __restrict__ h2,
                                             const float* __restrict__ sc,
                                             const float* __restrict__ sh,
                                             float* __restrict__ out) {
    __shared__ float tile[64][129];
    __shared__ float lsc[128], lsh[128];
    int t = threadIdx.x;
    int bb = blockIdx.y, n0 = blockIdx.x * 64;
    if (t < 128) { lsc[t] = sc[t]; lsh[t] = sh[t]; }
    #pragma unroll
    for (int i = 0; i < 8; i++) {               // load 64 rows x 128 ch
        int fq = t + i * 256;
        int row = fq >> 5;
        int c4 = (fq & 31) * 4;
        float4 v = *(const float4*)(h2 + ((size_t)(bb * Nn + n0 + row)) * 128 + c4);
        tile[row][c4 + 0] = v.x; tile[row][c4 + 1] = v.y;
        tile[row][c4 + 2] = v.z; tile[row][c4 + 3] = v.w;
    }
    __syncthreads();
    int j = t & 63, og = t >> 6;                // lanes sweep n for coalesced writes
    #pragma unroll
    for (int o = og; o < 128; o += 4) {
        float v = fmaxf(0.f, fmaf(tile[j][o], lsc[o], lsh[o]));
        out[((size_t)(bb * 128 + o)) * Nn + n0 + j] = v;
    }
}

extern "C" void kernel_launch(void* const* d_in, const int* in_sizes, int n_in,
                              void* d_out, int out_size, void* d_ws, size_t ws_size,
                              hipStream_t stream) {
    const float* x    = (const float*)d_in[0];
    const int*   gidx = (const int*)d_in[1];
    const int*   fps  = (const int*)d_in[2];
    // d_in[3] = N (16384), known statically
    const float* w1   = (const float*)d_in[4];
    const float* b1   = (const float*)d_in[5];
    const float* g1   = (const float*)d_in[6];
    const float* be1  = (const float*)d_in[7];
    const float* w2   = (const float*)d_in[8];
    const float* b2   = (const float*)d_in[9];
    const float* g2   = (const float*)d_in[10];
    const float* be2  = (const float*)d_in[11];
    float* out = (float*)d_out;

    char* ws = (char*)d_ws;
    unsigned int* seg  = (unsigned int*)(ws + OFF_SEG);
    float* segf        = (float*)(ws + OFF_SEG);
    float* gx          = (float*)(ws + OFF_GX);
    float* h1          = (float*)(ws + OFF_H1);
    float* h2          = (float*)(ws + OFF_H2);
    unsigned char* flg = (unsigned char*)(ws + OFF_FLAGS);
    float* part        = (float*)(ws + OFF_PART);
    float* sc1         = (float*)(ws + OFF_SC1);
    float* sh1         = (float*)(ws + OFF_SH1);
    float* sc2         = (float*)(ws + OFF_SC2);
    float* sh2         = (float*)(ws + OFF_SH2);

    hipMemsetAsync(seg, 0, SZ_SEG, stream);
    hipMemsetAsync(flg, 0, SZ_FLAGS, stream);
    k_setflags<<<64, 256, 0, stream>>>(fps, flg);
    k_groupmax_scatter<<<dim3(Nn, Bb), 256, 0, stream>>>(x, gidx, flg, gx, seg);
    k_gemm1<<<ROWS / 64, 256, 0, stream>>>(gx, segf, fps, w1, b1, h1);
    k_stats<<<64, 256, 0, stream>>>(h1, part);
    k_finalize<<<1, 128, 0, stream>>>(part, g1, be1, sc1, sh1);
    k_gemm2<<<ROWS / 64, 256, 0, stream>>>(h1, sc1, sh1, w2, b2, h2);
    k_stats<<<64, 256, 0, stream>>>(h2, part);
    k_finalize<<<1, 128, 0, stream>>>(part, g2, be2, sc2, sh2);
    k_out<<<dim3(Nn / 64, Bb), 256, 0, stream>>>(h2, sc2, sh2, out);
}

// Round 3
// 244.723 us; speedup vs baseline: 1.7189x; 1.7189x over previous
//
#include <hip/hip_runtime.h>

// Problem dims (fixed by setup_inputs)
constexpr int Bb = 4, Cc = 128, Nn = 4096, Kk = 32, Ns = 16384;
constexpr int ROWS = Bb * Nn; // 16384 (b*n) rows

// ---- workspace layout (bytes) ----
constexpr size_t SZ_SEG   = (size_t)Bb * Ns * Cc * 4;   // 32 MB: scatter-max targets (u32 bits of f32)
constexpr size_t OFF_SEG  = 0;
constexpr size_t SZ_GX    = (size_t)ROWS * Cc * 4;      // 8 MB
constexpr size_t OFF_GX   = OFF_SEG + SZ_SEG;           // group-max, row-major (row, c)
constexpr size_t OFF_H1   = OFF_GX + SZ_GX;             // GEMM1 out (row, 128)
constexpr size_t OFF_H2   = OFF_H1 + SZ_GX;             // GEMM2 out (row, 128)
constexpr size_t SZ_FLAGS = (size_t)Bb * Ns;            // 64 KB needed-segment flags
constexpr size_t OFF_FLAGS= OFF_H2 + SZ_GX;
constexpr size_t SZ_PART  = 2 * 128 * 128 * 4;          // 128 KB stats partials
constexpr size_t OFF_PART = OFF_FLAGS + SZ_FLAGS;
constexpr size_t OFF_SC1  = OFF_PART + SZ_PART;
constexpr size_t OFF_SH1  = OFF_SC1 + 512;
constexpr size_t OFF_SC2  = OFF_SH1 + 512;
constexpr size_t OFF_SH2  = OFF_SC2 + 512;

// ---- mark segments that will actually be gathered (fps targets) ----
__global__ void k_setflags(const int* __restrict__ fps, unsigned char* __restrict__ flags) {
    int i = blockIdx.x * 256 + threadIdx.x;     // 0 .. 16383
    if (i < Bb * Nn) {
        int bb = i >> 12;                        // / 4096
        flags[bb * Ns + fps[i]] = 1;
    }
}

// ---- fused: local max over k  +  filtered scatter-max into seg ----
// grid (4096, 4), 256 threads. Block handles one (b, n): 128 channels x 32 k.
// Thread t: channel cq = t>>3 (+32 per pass), k-quad k4 = (t&7)*4.
// One float4 load per (channel, pass); 3-shuffle reduce over the 8-lane group.
__global__ __launch_bounds__(256) void k_groupmax_scatter(
        const float* __restrict__ x, const int* __restrict__ gidx,
        const unsigned char* __restrict__ flags,
        float* __restrict__ gx, unsigned int* __restrict__ seg) {
    int nn = blockIdx.x, bb = blockIdx.y;
    int t = threadIdx.x;
    __shared__ float gbuf[128];
    __shared__ unsigned int srow[32];   // seg row base per k, 0xFFFFFFFF = not needed

    if (t < 32) {
        int idxv = gidx[((bb * Nn + nn) << 5) + t];
        bool need = flags[bb * Ns + idxv] != 0;
        srow[t] = need ? (unsigned int)(bb * Ns + idxv) * 128u : 0xFFFFFFFFu;
    }
    __syncthreads();

    int k4 = (t & 7) * 4;
    int cq = t >> 3;                    // 0..31
    unsigned int s0 = srow[k4 + 0], s1 = srow[k4 + 1];
    unsigned int s2 = srow[k4 + 2], s3 = srow[k4 + 3];

    const float* xb = x + ((size_t)bb * Cc) * (Nn * Kk) + (size_t)nn * Kk;
    float4 v[4];
    #pragma unroll
    for (int p = 0; p < 4; p++)
        v[p] = *(const float4*)(xb + (size_t)(cq + p * 32) * (Nn * Kk) + k4);

    #pragma unroll
    for (int p = 0; p < 4; p++) {
        int ch = cq + p * 32;
        float4 w = v[p];
        float m = fmaxf(fmaxf(w.x, w.y), fmaxf(w.z, w.w));
        m = fmaxf(m, __shfl_xor(m, 1, 64));
        m = fmaxf(m, __shfl_xor(m, 2, 64));
        m = fmaxf(m, __shfl_xor(m, 4, 64));
        if ((t & 7) == 0) gbuf[ch] = m;
        if (s0 != 0xFFFFFFFFu && w.x > 0.f) atomicMax(seg + s0 + ch, __float_as_uint(w.x));
        if (s1 != 0xFFFFFFFFu && w.y > 0.f) atomicMax(seg + s1 + ch, __float_as_uint(w.y));
        if (s2 != 0xFFFFFFFFu && w.z > 0.f) atomicMax(seg + s2 + ch, __float_as_uint(w.z));
        if (s3 != 0xFFFFFFFFu && w.w > 0.f) atomicMax(seg + s3 + ch, __float_as_uint(w.w));
    }
    __syncthreads();
    if (t < 128) gx[((size_t)(bb * Nn + nn)) * 128 + t] = gbuf[t];
}

// ---- GEMM1: h1(row,128) = A(row,256) @ w1^T + b1 ----
// A: k<128 -> gx[row][k]; k>=128 -> seg[fps_row][k-128] (gather fused here)
__global__ __launch_bounds__(256) void k_gemm1(
        const float* __restrict__ gx, const float* __restrict__ segf,
        const int* __restrict__ fps, const float* __restrict__ w1,
        const float* __restrict__ b1, float* __restrict__ h1) {
    __shared__ float As[32][68];    // [kc][row], 64 rows + pad
    __shared__ float Bs[32][132];   // [kc][col], 128 cols + pad
    __shared__ int rowbase[64];
    int t = threadIdx.x;
    int m0 = blockIdx.x * 64;
    if (t < 64) {
        int row = m0 + t;
        rowbase[t] = ((row >> 12) * Ns + fps[row]) * 128;
    }
    int tn = t & 31;    // cols tn*4..+3
    int tm = t >> 5;    // rows tm*8..+7
    float acc[8][4] = {};
    for (int k0 = 0; k0 < 256; k0 += 32) {
        __syncthreads();
        #pragma unroll
        for (int i = 0; i < 2; i++) {           // A: 2048 floats
            int fq = t + i * 256;
            int row = fq >> 3;
            int c4 = (fq & 7) * 4;
            int k = k0 + c4;
            float4 v;
            if (k0 < 128) v = *(const float4*)(gx + (size_t)(m0 + row) * 128 + k);
            else          v = *(const float4*)(segf + rowbase[row] + (k - 128));
            As[c4 + 0][row] = v.x; As[c4 + 1][row] = v.y;
            As[c4 + 2][row] = v.z; As[c4 + 3][row] = v.w;
        }
        #pragma unroll
        for (int i = 0; i < 4; i++) {           // B: w1 chunk 32x128
            int fq = t + i * 256;
            int col = fq >> 3;
            int c4 = (fq & 7) * 4;
            float4 v = *(const float4*)(w1 + (size_t)col * 256 + k0 + c4);
            Bs[c4 + 0][col] = v.x; Bs[c4 + 1][col] = v.y;
            Bs[c4 + 2][col] = v.z; Bs[c4 + 3][col] = v.w;
        }
        __syncthreads();
        #pragma unroll
        for (int kc = 0; kc < 32; kc++) {
            float4 a0 = *(const float4*)&As[kc][tm * 8];
            float4 a1 = *(const float4*)&As[kc][tm * 8 + 4];
            float4 bv = *(const float4*)&Bs[kc][tn * 4];
            float av[8] = {a0.x, a0.y, a0.z, a0.w, a1.x, a1.y, a1.z, a1.w};
            float bw[4] = {bv.x, bv.y, bv.z, bv.w};
            #pragma unroll
            for (int r = 0; r < 8; r++)
                #pragma unroll
                for (int c = 0; c < 4; c++) acc[r][c] += av[r] * bw[c];
        }
    }
    float4 bv = *(const float4*)(b1 + tn * 4);
    #pragma unroll
    for (int r = 0; r < 8; r++) {
        int row = m0 + tm * 8 + r;
        float4 o;
        o.x = acc[r][0] + bv.x; o.y = acc[r][1] + bv.y;
        o.z = acc[r][2] + bv.z; o.w = acc[r][3] + bv.w;
        *(float4*)(h1 + (size_t)row * 128 + tn * 4) = o;
    }
}

// ---- GEMM2: h2(row,128) = relu(bn1(h1)) @ w2^T + b2 ----
__global__ __launch_bounds__(256) void k_gemm2(
        const float* __restrict__ h1, const float* __restrict__ sc1,
        const float* __restrict__ sh1, const float* __restrict__ w2,
        const float* __restrict__ b2, float* __restrict__ h2) {
    __shared__ float As[32][68];
    __shared__ float Bs[32][132];
    __shared__ float ssc[128], ssh[128];
    int t = threadIdx.x;
    int m0 = blockIdx.x * 64;
    if (t < 128) { ssc[t] = sc1[t]; ssh[t] = sh1[t]; }
    int tn = t & 31, tm = t >> 5;
    float acc[8][4] = {};
    for (int k0 = 0; k0 < 128; k0 += 32) {
        __syncthreads();
        #pragma unroll
        for (int i = 0; i < 2; i++) {
            int fq = t + i * 256;
            int row = fq >> 3;
            int c4 = (fq & 7) * 4;
            int k = k0 + c4;
            float4 v = *(const float4*)(h1 + (size_t)(m0 + row) * 128 + k);
            As[c4 + 0][row] = fmaxf(0.f, fmaf(v.x, ssc[k + 0], ssh[k + 0]));
            As[c4 + 1][row] = fmaxf(0.f, fmaf(v.y, ssc[k + 1], ssh[k + 1]));
            As[c4 + 2][row] = fmaxf(0.f, fmaf(v.z, ssc[k + 2], ssh[k + 2]));
            As[c4 + 3][row] = fmaxf(0.f, fmaf(v.w, ssc[k + 3], ssh[k + 3]));
        }
        #pragma unroll
        for (int i = 0; i < 4; i++) {
            int fq = t + i * 256;
            int col = fq >> 3;
            int c4 = (fq & 7) * 4;
            float4 v = *(const float4*)(w2 + (size_t)col * 128 + k0 + c4);
            Bs[c4 + 0][col] = v.x; Bs[c4 + 1][col] = v.y;
            Bs[c4 + 2][col] = v.z; Bs[c4 + 3][col] = v.w;
        }
        __syncthreads();
        #pragma unroll
        for (int kc = 0; kc < 32; kc++) {
            float4 a0 = *(const float4*)&As[kc][tm * 8];
            float4 a1 = *(const float4*)&As[kc][tm * 8 + 4];
            float4 bv = *(const float4*)&Bs[kc][tn * 4];
            float av[8] = {a0.x, a0.y, a0.z, a0.w, a1.x, a1.y, a1.z, a1.w};
            float bw[4] = {bv.x, bv.y, bv.z, bv.w};
            #pragma unroll
            for (int r = 0; r < 8; r++)
                #pragma unroll
                for (int c = 0; c < 4; c++) acc[r][c] += av[r] * bw[c];
        }
    }
    float4 bv = *(const float4*)(b2 + tn * 4);
    #pragma unroll
    for (int r = 0; r < 8; r++) {
        int row = m0 + tm * 8 + r;
        float4 o;
        o.x = acc[r][0] + bv.x; o.y = acc[r][1] + bv.y;
        o.z = acc[r][2] + bv.z; o.w = acc[r][3] + bv.w;
        *(float4*)(h2 + (size_t)row * 128 + tn * 4) = o;
    }
}

// ---- BN stats stage 1: 64 blocks x 256 thr; block reduces 256 rows ----
__global__ __launch_bounds__(256) void k_stats(const float* __restrict__ h,
                                               float* __restrict__ partial) {
    int o = threadIdx.x & 127, rp = threadIdx.x >> 7;
    int blk = blockIdx.x;
    float s = 0.f, sq = 0.f;
    for (int r = blk * 256 + rp; r < blk * 256 + 256; r += 2) {
        float v = h[(size_t)r * 128 + o];
        s += v; sq += v * v;
    }
    partial[(blk * 2 + rp) * 128 + o] = s;
    partial[16384 + (blk * 2 + rp) * 128 + o] = sq;
}

// ---- BN stats stage 2: 1 block x 128 thr -> scale/shift ----
__global__ void k_finalize(const float* __restrict__ partial,
                           const float* __restrict__ g, const float* __restrict__ be,
                           float* __restrict__ scale, float* __restrict__ shift) {
    int o = threadIdx.x;
    float s = 0.f, sq = 0.f;
    for (int j = 0; j < 128; j++) { s += partial[j * 128 + o]; sq += partial[16384 + j * 128 + o]; }
    float mean = s * (1.0f / 16384.0f);
    float var = sq * (1.0f / 16384.0f) - mean * mean;
    float sc = g[o] * rsqrtf(var + 1e-5f);
    scale[o] = sc;
    shift[o] = be[o] - mean * sc;
}

// ---- final: bn2+relu on h2, transpose to (b, c, n) ----
__global__ __launch_bounds__(256) void k_out(const float* __restrict__ h2,
                                             const float* __restrict__ sc,
                                             const float* __restrict__ sh,
                                             float* __restrict__ out) {
    __shared__ float tile[64][129];
    __shared__ float lsc[128], lsh[128];
    int t = threadIdx.x;
    int bb = blockIdx.y, n0 = blockIdx.x * 64;
    if (t < 128) { lsc[t] = sc[t]; lsh[t] = sh[t]; }
    #pragma unroll
    for (int i = 0; i < 8; i++) {               // load 64 rows x 128 ch
        int fq = t + i * 256;
        int row = fq >> 5;
        int c4 = (fq & 31) * 4;
        float4 v = *(const float4*)(h2 + ((size_t)(bb * Nn + n0 + row)) * 128 + c4);
        tile[row][c4 + 0] = v.x; tile[row][c4 + 1] = v.y;
        tile[row][c4 + 2] = v.z; tile[row][c4 + 3] = v.w;
    }
    __syncthreads();
    int j = t & 63, og = t >> 6;                // lanes sweep n for coalesced writes
    #pragma unroll
    for (int o = og; o < 128; o += 4) {
        float v = fmaxf(0.f, fmaf(tile[j][o], lsc[o], lsh[o]));
        out[((size_t)(bb * 128 + o)) * Nn + n0 + j] = v;
    }
}

extern "C" void kernel_launch(void* const* d_in, const int* in_sizes, int n_in,
                              void* d_out, int out_size, void* d_ws, size_t ws_size,
                              hipStream_t stream) {
    const float* x    = (const float*)d_in[0];
    const int*   gidx = (const int*)d_in[1];
    const int*   fps  = (const int*)d_in[2];
    // d_in[3] = N (16384), known statically
    const float* w1   = (const float*)d_in[4];
    const float* b1   = (const float*)d_in[5];
    const float* g1   = (const float*)d_in[6];
    const float* be1  = (const float*)d_in[7];
    const float* w2   = (const float*)d_in[8];
    const float* b2   = (const float*)d_in[9];
    const float* g2   = (const float*)d_in[10];
    const float* be2  = (const float*)d_in[11];
    float* out = (float*)d_out;

    char* ws = (char*)d_ws;
    unsigned int* seg  = (unsigned int*)(ws + OFF_SEG);
    float* segf        = (float*)(ws + OFF_SEG);
    float* gx          = (float*)(ws + OFF_GX);
    float* h1          = (float*)(ws + OFF_H1);
    float* h2          = (float*)(ws + OFF_H2);
    unsigned char* flg = (unsigned char*)(ws + OFF_FLAGS);
    float* part        = (float*)(ws + OFF_PART);
    float* sc1         = (float*)(ws + OFF_SC1);
    float* sh1         = (float*)(ws + OFF_SH1);
    float* sc2         = (float*)(ws + OFF_SC2);
    float* sh2         = (float*)(ws + OFF_SH2);

    hipMemsetAsync(seg, 0, SZ_SEG, stream);
    hipMemsetAsync(flg, 0, SZ_FLAGS, stream);
    k_setflags<<<64, 256, 0, stream>>>(fps, flg);
    k_groupmax_scatter<<<dim3(Nn, Bb), 256, 0, stream>>>(x, gidx, flg, gx, seg);
    k_gemm1<<<ROWS / 64, 256, 0, stream>>>(gx, segf, fps, w1, b1, h1);
    k_stats<<<64, 256, 0, stream>>>(h1, part);
    k_finalize<<<1, 128, 0, stream>>>(part, g1, be1, sc1, sh1);
    k_gemm2<<<ROWS / 64, 256, 0, stream>>>(h1, sc1, sh1, w2, b2, h2);
    k_stats<<<64, 256, 0, stream>>>(h2, part);
    k_finalize<<<1, 128, 0, stream>>>(part, g2, be2, sc2, sh2);
    k_out<<<dim3(Nn / 64, Bb), 256, 0, stream>>>(h2, sc2, sh2, out);
}

// Round 4
// 243.906 us; speedup vs baseline: 1.7247x; 1.0033x over previous
//
#include <hip/hip_runtime.h>

// Problem dims (fixed by setup_inputs)
constexpr int Bb = 4, Cc = 128, Nn = 4096, Kk = 32, Ns = 16384;
constexpr int ROWS = Bb * Nn; // 16384 (b*n) rows

// ---- workspace layout (bytes) ----
constexpr size_t SZ_SEG   = (size_t)Bb * Ns * Cc * 4;   // 32 MB: scatter-max targets (u32 bits of f32)
constexpr size_t OFF_SEG  = 0;
constexpr size_t SZ_GX    = (size_t)ROWS * Cc * 4;      // 8 MB
constexpr size_t OFF_GX   = OFF_SEG + SZ_SEG;           // group-max, row-major (row, c)
constexpr size_t OFF_H1   = OFF_GX + SZ_GX;             // GEMM1 out (row, 128)
constexpr size_t OFF_H2   = OFF_H1 + SZ_GX;             // GEMM2 out (row, 128)
constexpr size_t SZ_FLAGS = (size_t)Bb * Ns;            // 64 KB needed-segment flags
constexpr size_t OFF_FLAGS= OFF_H2 + SZ_GX;
constexpr size_t SZ_PART  = 2 * 128 * 128 * 4;          // 128 KB stats partials
constexpr size_t OFF_PART = OFF_FLAGS + SZ_FLAGS;
constexpr size_t OFF_SC1  = OFF_PART + SZ_PART;
constexpr size_t OFF_SH1  = OFF_SC1 + 512;
constexpr size_t OFF_SC2  = OFF_SH1 + 512;
constexpr size_t OFF_SH2  = OFF_SC2 + 512;

// ---- mark segments that will actually be gathered (fps targets) ----
__global__ void k_setflags(const int* __restrict__ fps, unsigned char* __restrict__ flags) {
    int i = blockIdx.x * 256 + threadIdx.x;     // 0 .. 16383
    if (i < Bb * Nn) {
        int bb = i >> 12;                        // / 4096
        flags[bb * Ns + fps[i]] = 1;
    }
}

// ---- zero exactly the segment rows that will be gathered (<= 8 MB writes) ----
// Replaces a 32 MB runtime fill (rocclr fillBuffer was 152 us at 10% occupancy).
// Duplicate rows write 0 redundantly before any atomic runs - benign.
__global__ __launch_bounds__(256) void k_zeroseg(const int* __restrict__ fps,
                                                 float4* __restrict__ seg4) {
    int i = blockIdx.x * 8 + (threadIdx.x >> 5);    // gather-row index 0..16383
    int lane = threadIdx.x & 31;
    int bb = i >> 12;
    size_t row = (size_t)bb * Ns + fps[i];
    seg4[row * 32 + lane] = float4{0.f, 0.f, 0.f, 0.f};
}

// ---- fused: local max over k  +  filtered scatter-max into seg ----
// grid (4096, 4), 256 threads. Block handles one (b, n): 128 channels x 32 k.
// Thread t: channel cq = t>>3 (+32 per pass), k-quad k4 = (t&7)*4.
// One float4 load per (channel, pass); 3-shuffle reduce over the 8-lane group.
__global__ __launch_bounds__(256) void k_groupmax_scatter(
        const float* __restrict__ x, const int* __restrict__ gidx,
        const unsigned char* __restrict__ flags,
        float* __restrict__ gx, unsigned int* __restrict__ seg) {
    int nn = blockIdx.x, bb = blockIdx.y;
    int t = threadIdx.x;
    __shared__ float gbuf[128];
    __shared__ unsigned int srow[32];   // seg row base per k, 0xFFFFFFFF = not needed

    if (t < 32) {
        int idxv = gidx[((bb * Nn + nn) << 5) + t];
        bool need = flags[bb * Ns + idxv] != 0;
        srow[t] = need ? (unsigned int)(bb * Ns + idxv) * 128u : 0xFFFFFFFFu;
    }
    __syncthreads();

    int k4 = (t & 7) * 4;
    int cq = t >> 3;                    // 0..31
    unsigned int s0 = srow[k4 + 0], s1 = srow[k4 + 1];
    unsigned int s2 = srow[k4 + 2], s3 = srow[k4 + 3];

    const float* xb = x + ((size_t)bb * Cc) * (Nn * Kk) + (size_t)nn * Kk;
    float4 v[4];
    #pragma unroll
    for (int p = 0; p < 4; p++)
        v[p] = *(const float4*)(xb + (size_t)(cq + p * 32) * (Nn * Kk) + k4);

    #pragma unroll
    for (int p = 0; p < 4; p++) {
        int ch = cq + p * 32;
        float4 w = v[p];
        float m = fmaxf(fmaxf(w.x, w.y), fmaxf(w.z, w.w));
        m = fmaxf(m, __shfl_xor(m, 1, 64));
        m = fmaxf(m, __shfl_xor(m, 2, 64));
        m = fmaxf(m, __shfl_xor(m, 4, 64));
        if ((t & 7) == 0) gbuf[ch] = m;
        if (s0 != 0xFFFFFFFFu && w.x > 0.f) atomicMax(seg + s0 + ch, __float_as_uint(w.x));
        if (s1 != 0xFFFFFFFFu && w.y > 0.f) atomicMax(seg + s1 + ch, __float_as_uint(w.y));
        if (s2 != 0xFFFFFFFFu && w.z > 0.f) atomicMax(seg + s2 + ch, __float_as_uint(w.z));
        if (s3 != 0xFFFFFFFFu && w.w > 0.f) atomicMax(seg + s3 + ch, __float_as_uint(w.w));
    }
    __syncthreads();
    if (t < 128) gx[((size_t)(bb * Nn + nn)) * 128 + t] = gbuf[t];
}

// ---- GEMM1: h1(row,128) = A(row,256) @ w1^T + b1 ----
// A: k<128 -> gx[row][k]; k>=128 -> seg[fps_row][k-128] (gather fused here)
__global__ __launch_bounds__(256) void k_gemm1(
        const float* __restrict__ gx, const float* __restrict__ segf,
        const int* __restrict__ fps, const float* __restrict__ w1,
        const float* __restrict__ b1, float* __restrict__ h1) {
    __shared__ float As[32][68];    // [kc][row], 64 rows + pad
    __shared__ float Bs[32][132];   // [kc][col], 128 cols + pad
    __shared__ int rowbase[64];
    int t = threadIdx.x;
    int m0 = blockIdx.x * 64;
    if (t < 64) {
        int row = m0 + t;
        rowbase[t] = ((row >> 12) * Ns + fps[row]) * 128;
    }
    int tn = t & 31;    // cols tn*4..+3
    int tm = t >> 5;    // rows tm*8..+7
    float acc[8][4] = {};
    for (int k0 = 0; k0 < 256; k0 += 32) {
        __syncthreads();
        #pragma unroll
        for (int i = 0; i < 2; i++) {           // A: 2048 floats
            int fq = t + i * 256;
            int row = fq >> 3;
            int c4 = (fq & 7) * 4;
            int k = k0 + c4;
            float4 v;
            if (k0 < 128) v = *(const float4*)(gx + (size_t)(m0 + row) * 128 + k);
            else          v = *(const float4*)(segf + rowbase[row] + (k - 128));
            As[c4 + 0][row] = v.x; As[c4 + 1][row] = v.y;
            As[c4 + 2][row] = v.z; As[c4 + 3][row] = v.w;
        }
        #pragma unroll
        for (int i = 0; i < 4; i++) {           // B: w1 chunk 32x128
            int fq = t + i * 256;
            int col = fq >> 3;
            int c4 = (fq & 7) * 4;
            float4 v = *(const float4*)(w1 + (size_t)col * 256 + k0 + c4);
            Bs[c4 + 0][col] = v.x; Bs[c4 + 1][col] = v.y;
            Bs[c4 + 2][col] = v.z; Bs[c4 + 3][col] = v.w;
        }
        __syncthreads();
        #pragma unroll
        for (int kc = 0; kc < 32; kc++) {
            float4 a0 = *(const float4*)&As[kc][tm * 8];
            float4 a1 = *(const float4*)&As[kc][tm * 8 + 4];
            float4 bv = *(const float4*)&Bs[kc][tn * 4];
            float av[8] = {a0.x, a0.y, a0.z, a0.w, a1.x, a1.y, a1.z, a1.w};
            float bw[4] = {bv.x, bv.y, bv.z, bv.w};
            #pragma unroll
            for (int r = 0; r < 8; r++)
                #pragma unroll
                for (int c = 0; c < 4; c++) acc[r][c] += av[r] * bw[c];
        }
    }
    float4 bv = *(const float4*)(b1 + tn * 4);
    #pragma unroll
    for (int r = 0; r < 8; r++) {
        int row = m0 + tm * 8 + r;
        float4 o;
        o.x = acc[r][0] + bv.x; o.y = acc[r][1] + bv.y;
        o.z = acc[r][2] + bv.z; o.w = acc[r][3] + bv.w;
        *(float4*)(h1 + (size_t)row * 128 + tn * 4) = o;
    }
}

// ---- GEMM2: h2(row,128) = relu(bn1(h1)) @ w2^T + b2 ----
__global__ __launch_bounds__(256) void k_gemm2(
        const float* __restrict__ h1, const float* __restrict__ sc1,
        const float* __restrict__ sh1, const float* __restrict__ w2,
        const float* __restrict__ b2, float* __restrict__ h2) {
    __shared__ float As[32][68];
    __shared__ float Bs[32][132];
    __shared__ float ssc[128], ssh[128];
    int t = threadIdx.x;
    int m0 = blockIdx.x * 64;
    if (t < 128) { ssc[t] = sc1[t]; ssh[t] = sh1[t]; }
    int tn = t & 31, tm = t >> 5;
    float acc[8][4] = {};
    for (int k0 = 0; k0 < 128; k0 += 32) {
        __syncthreads();
        #pragma unroll
        for (int i = 0; i < 2; i++) {
            int fq = t + i * 256;
            int row = fq >> 3;
            int c4 = (fq & 7) * 4;
            int k = k0 + c4;
            float4 v = *(const float4*)(h1 + (size_t)(m0 + row) * 128 + k);
            As[c4 + 0][row] = fmaxf(0.f, fmaf(v.x, ssc[k + 0], ssh[k + 0]));
            As[c4 + 1][row] = fmaxf(0.f, fmaf(v.y, ssc[k + 1], ssh[k + 1]));
            As[c4 + 2][row] = fmaxf(0.f, fmaf(v.z, ssc[k + 2], ssh[k + 2]));
            As[c4 + 3][row] = fmaxf(0.f, fmaf(v.w, ssc[k + 3], ssh[k + 3]));
        }
        #pragma unroll
        for (int i = 0; i < 4; i++) {
            int fq = t + i * 256;
            int col = fq >> 3;
            int c4 = (fq & 7) * 4;
            float4 v = *(const float4*)(w2 + (size_t)col * 128 + k0 + c4);
            Bs[c4 + 0][col] = v.x; Bs[c4 + 1][col] = v.y;
            Bs[c4 + 2][col] = v.z; Bs[c4 + 3][col] = v.w;
        }
        __syncthreads();
        #pragma unroll
        for (int kc = 0; kc < 32; kc++) {
            float4 a0 = *(const float4*)&As[kc][tm * 8];
            float4 a1 = *(const float4*)&As[kc][tm * 8 + 4];
            float4 bv = *(const float4*)&Bs[kc][tn * 4];
            float av[8] = {a0.x, a0.y, a0.z, a0.w, a1.x, a1.y, a1.z, a1.w};
            float bw[4] = {bv.x, bv.y, bv.z, bv.w};
            #pragma unroll
            for (int r = 0; r < 8; r++)
                #pragma unroll
                for (int c = 0; c < 4; c++) acc[r][c] += av[r] * bw[c];
        }
    }
    float4 bv = *(const float4*)(b2 + tn * 4);
    #pragma unroll
    for (int r = 0; r < 8; r++) {
        int row = m0 + tm * 8 + r;
        float4 o;
        o.x = acc[r][0] + bv.x; o.y = acc[r][1] + bv.y;
        o.z = acc[r][2] + bv.z; o.w = acc[r][3] + bv.w;
        *(float4*)(h2 + (size_t)row * 128 + tn * 4) = o;
    }
}

// ---- BN stats stage 1: 64 blocks x 256 thr; block reduces 256 rows ----
__global__ __launch_bounds__(256) void k_stats(const float* __restrict__ h,
                                               float* __restrict__ partial) {
    int o = threadIdx.x & 127, rp = threadIdx.x >> 7;
    int blk = blockIdx.x;
    float s = 0.f, sq = 0.f;
    for (int r = blk * 256 + rp; r < blk * 256 + 256; r += 2) {
        float v = h[(size_t)r * 128 + o];
        s += v; sq += v * v;
    }
    partial[(blk * 2 + rp) * 128 + o] = s;
    partial[16384 + (blk * 2 + rp) * 128 + o] = sq;
}

// ---- BN stats stage 2: 1 block x 128 thr -> scale/shift ----
__global__ void k_finalize(const float* __restrict__ partial,
                           const float* __restrict__ g, const float* __restrict__ be,
                           float* __restrict__ scale, float* __restrict__ shift) {
    int o = threadIdx.x;
    float s = 0.f, sq = 0.f;
    for (int j = 0; j < 128; j++) { s += partial[j * 128 + o]; sq += partial[16384 + j * 128 + o]; }
    float mean = s * (1.0f / 16384.0f);
    float var = sq * (1.0f / 16384.0f) - mean * mean;
    float sc = g[o] * rsqrtf(var + 1e-5f);
    scale[o] = sc;
    shift[o] = be[o] - mean * sc;
}

// ---- final: bn2+relu on h2, transpose to (b, c, n) ----
__global__ __launch_bounds__(256) void k_out(const float* __restrict__ h2,
                                             const float* __restrict__ sc,
                                             const float* __restrict__ sh,
                                             float* __restrict__ out) {
    __shared__ float tile[64][129];
    __shared__ float lsc[128], lsh[128];
    int t = threadIdx.x;
    int bb = blockIdx.y, n0 = blockIdx.x * 64;
    if (t < 128) { lsc[t] = sc[t]; lsh[t] = sh[t]; }
    #pragma unroll
    for (int i = 0; i < 8; i++) {               // load 64 rows x 128 ch
        int fq = t + i * 256;
        int row = fq >> 5;
        int c4 = (fq & 31) * 4;
        float4 v = *(const float4*)(h2 + ((size_t)(bb * Nn + n0 + row)) * 128 + c4);
        tile[row][c4 + 0] = v.x; tile[row][c4 + 1] = v.y;
        tile[row][c4 + 2] = v.z; tile[row][c4 + 3] = v.w;
    }
    __syncthreads();
    int j = t & 63, og = t >> 6;                // lanes sweep n for coalesced writes
    #pragma unroll
    for (int o = og; o < 128; o += 4) {
        float v = fmaxf(0.f, fmaf(tile[j][o], lsc[o], lsh[o]));
        out[((size_t)(bb * 128 + o)) * Nn + n0 + j] = v;
    }
}

extern "C" void kernel_launch(void* const* d_in, const int* in_sizes, int n_in,
                              void* d_out, int out_size, void* d_ws, size_t ws_size,
                              hipStream_t stream) {
    const float* x    = (const float*)d_in[0];
    const int*   gidx = (const int*)d_in[1];
    const int*   fps  = (const int*)d_in[2];
    // d_in[3] = N (16384), known statically
    const float* w1   = (const float*)d_in[4];
    const float* b1   = (const float*)d_in[5];
    const float* g1   = (const float*)d_in[6];
    const float* be1  = (const float*)d_in[7];
    const float* w2   = (const float*)d_in[8];
    const float* b2   = (const float*)d_in[9];
    const float* g2   = (const float*)d_in[10];
    const float* be2  = (const float*)d_in[11];
    float* out = (float*)d_out;

    char* ws = (char*)d_ws;
    unsigned int* seg  = (unsigned int*)(ws + OFF_SEG);
    float* segf        = (float*)(ws + OFF_SEG);
    float4* seg4       = (float4*)(ws + OFF_SEG);
    float* gx          = (float*)(ws + OFF_GX);
    float* h1          = (float*)(ws + OFF_H1);
    float* h2          = (float*)(ws + OFF_H2);
    unsigned char* flg = (unsigned char*)(ws + OFF_FLAGS);
    float* part        = (float*)(ws + OFF_PART);
    float* sc1         = (float*)(ws + OFF_SC1);
    float* sh1         = (float*)(ws + OFF_SH1);
    float* sc2         = (float*)(ws + OFF_SC2);
    float* sh2         = (float*)(ws + OFF_SH2);

    hipMemsetAsync(flg, 0, SZ_FLAGS, stream);
    k_setflags<<<64, 256, 0, stream>>>(fps, flg);
    k_zeroseg<<<ROWS / 8, 256, 0, stream>>>(fps, seg4);
    k_groupmax_scatter<<<dim3(Nn, Bb), 256, 0, stream>>>(x, gidx, flg, gx, seg);
    k_gemm1<<<ROWS / 64, 256, 0, stream>>>(gx, segf, fps, w1, b1, h1);
    k_stats<<<64, 256, 0, stream>>>(h1, part);
    k_finalize<<<1, 128, 0, stream>>>(part, g1, be1, sc1, sh1);
    k_gemm2<<<ROWS / 64, 256, 0, stream>>>(h1, sc1, sh1, w2, b2, h2);
    k_stats<<<64, 256, 0, stream>>>(h2, part);
    k_finalize<<<1, 128, 0, stream>>>(part, g2, be2, sc2, sh2);
    k_out<<<dim3(Nn / 64, Bb), 256, 0, stream>>>(h2, sc2, sh2, out);
}